// Round 12
// baseline (69.384 us; speedup 1.0000x reference)
//
#include <hip/hip_runtime.h>
#include <hip/hip_bf16.h>

// OuterAttention: A=B=8192, E1=E2=C=M=1024.
// logits_a = p1 @ sum(p2), logits_b = p2 @ sum(p1) -> no 8192^2 matrix.
// Round 12: 2 blocks/CU GEMM. BM=256 BN=128 BK=64 i8, grid 32x8x2=512 blocks,
// LDS 48.5KB/block, __launch_bounds__(512,4) (128 VGPR cap -> 16 waves/CU).
// Mechanism: co-resident block fills this block's barrier/vmcnt stalls (m114).

#define A_ROWS 8192
#define EDIM   1024
#define MDIM   1024

typedef __attribute__((ext_vector_type(8))) short bf16x8;
typedef __attribute__((ext_vector_type(4))) int i32x4;

// ---- workspace layout (bytes) ----
#define OFF_BIAS1   0ull
#define OFF_BIAS2   4096ull
#define OFF_S1      8192ull
#define OFF_S2      12288ull
#define OFF_LOGA    16384ull                  // 2 x 8192 floats (raw logits)
#define OFF_P1      81920ull                  // 8192*1024 i8 = 8 MB
#define OFF_P2      (OFF_P1 + 16777216ull)
#define OFF_SEQ1B   (OFF_P2 + 16777216ull)    // i8: 8 MB
#define OFF_SEQ2B   (OFF_SEQ1B + 16777216ull)
#define OFF_W1B     (OFF_SEQ2B + 16777216ull) // i8: 1 MB
#define OFF_W2B     (OFF_W1B + 2097152ull)

#define SA_INV 21.166666f        // 127/6   (seq quant)
#define SW_INV 4064.0f           // 127/(1/32)  (W quant)
#define SP_INV 25.4f             // 127/5   (P quant)
#define DQ_P   (5.0f / 127.0f)
#define DQ_A   (6.0f / 127.0f)

__device__ __forceinline__ unsigned pack4(float4 f, float s) {
  int q0 = __float2int_rn(f.x * s); q0 = q0 > 127 ? 127 : (q0 < -127 ? -127 : q0);
  int q1 = __float2int_rn(f.y * s); q1 = q1 > 127 ? 127 : (q1 < -127 ? -127 : q1);
  int q2 = __float2int_rn(f.z * s); q2 = q2 > 127 ? 127 : (q2 < -127 ? -127 : q2);
  int q3 = __float2int_rn(f.w * s); q3 = q3 > 127 ? 127 : (q3 < -127 ? -127 : q3);
  return (q0 & 255) | ((q1 & 255) << 8) | ((q2 & 255) << 16) | ((q3 & 255) << 24);
}

#define GLOAD16(src, dst) __builtin_amdgcn_global_load_lds( \
    (const __attribute__((address_space(1))) void*)(src),   \
    (__attribute__((address_space(3))) void*)(dst), 16, 0, 0)

// ---- prep: f32 -> i8 quantize (z=0..3) + ctx bias / S zero / out zero (z=4) ----
__global__ __launch_bounds__(256) void prep_k(
    const float* __restrict__ s1, const float* __restrict__ s2,
    const float* __restrict__ w1, const float* __restrict__ w2,
    uint2* __restrict__ s1o, uint2* __restrict__ s2o,
    uint2* __restrict__ w1o, uint2* __restrict__ w2o,
    const float* __restrict__ Wc1, const float* __restrict__ Wc2,
    const float* __restrict__ ctx, const float* __restrict__ b1,
    const float* __restrict__ b2, float* __restrict__ bias1,
    float* __restrict__ bias2, float* __restrict__ S1, float* __restrict__ S2,
    float* __restrict__ outz) {
  int z = blockIdx.z;
  if (z < 4) {
    const float* in = z == 0 ? s1 : z == 1 ? s2 : z == 2 ? w1 : w2;
    uint2* out = z == 0 ? s1o : z == 1 ? s2o : z == 2 ? w1o : w2o;
    float sc = z < 2 ? SA_INV : SW_INV;
    int n8 = z < 2 ? (A_ROWS * EDIM / 8) : (MDIM * EDIM / 8);
    int stride = gridDim.x * blockDim.x;
    for (int i = blockIdx.x * blockDim.x + threadIdx.x; i < n8; i += stride) {
      float4 fa = reinterpret_cast<const float4*>(in)[2 * i];
      float4 fb = reinterpret_cast<const float4*>(in)[2 * i + 1];
      out[i] = make_uint2(pack4(fa, sc), pack4(fb, sc));
    }
  } else {
    if (blockIdx.x == 0) {                       // zero the 2048-float output
      float4 zv = make_float4(0.f, 0.f, 0.f, 0.f);
      ((float4*)outz)[threadIdx.x] = zv;
      ((float4*)outz)[threadIdx.x + 256] = zv;
    }
    if (blockIdx.x >= 512) return;
    int zz = blockIdx.x >= 256;                  // 0: problem1, 1: problem2
    int bx = blockIdx.x & 255;
    const float* W = zz ? Wc2 : Wc1;
    const float* b = zz ? b2 : b1;
    float* bias = zz ? bias2 : bias1;
    float* S = zz ? S2 : S1;
    int wave = threadIdx.x >> 6, lane = threadIdx.x & 63;
    int m = bx * 4 + wave;
    const float4* wr = reinterpret_cast<const float4*>(W + (size_t)m * EDIM);
    const float4* cv = reinterpret_cast<const float4*>(ctx);
    float acc = 0.f;
#pragma unroll
    for (int ch = 0; ch < 4; ++ch) {
      float4 a = wr[ch * 64 + lane], d = cv[ch * 64 + lane];
      acc += a.x * d.x + a.y * d.y + a.z * d.z + a.w * d.w;
    }
    for (int o = 32; o; o >>= 1) acc += __shfl_down(acc, o);
    if (lane == 0) { bias[m] = acc + b[m]; S[m] = 0.f; }
  }
}

// ---- 256x128 i8 GEMM, BK=64, 2 blocks/CU ----
// 8 waves (4M x 2N), wave-tile 64x64, 16 K-tiles, dbuf.
// LDS bytes: A buf b @ b*16384 ([256][64] i8); B @ 32768 + b*8192 ([128][64]);
// scol f32[128] @ 49152. Swizzle: byte-in-64B-row ^= ((row>>1)&3)<<4.
// Per tile 3 loads (A=2, B=1); counted vmcnt(3); 3 barriers/tile.
__global__ __launch_bounds__(512, 4) void gemm8(
    const char* __restrict__ A1, const char* __restrict__ A2,
    const char* __restrict__ B1, const char* __restrict__ B2,
    const float* __restrict__ bias1, const float* __restrict__ bias2,
    char* __restrict__ P1, char* __restrict__ P2,
    float* __restrict__ S1, float* __restrict__ S2) {
  const int z = blockIdx.z;
  const char* __restrict__ Ab = z ? A2 : A1;
  const char* __restrict__ Bb = z ? B2 : B1;
  const float* __restrict__ bias = z ? bias2 : bias1;
  char* __restrict__ P = z ? P2 : P1;
  float* __restrict__ S = z ? S2 : S1;

  __shared__ __align__(16) char ldsb[49664];   // 48.5 KB -> 2 blocks/CU
  float* scol = (float*)(ldsb + 49152);

  const int tid = threadIdx.x;
  const int lane = tid & 63;
  const int wave = tid >> 6;
  const int wm = wave >> 1, wn = wave & 1;     // 4 M-quads x 2 N-halves
  const int r = lane & 15, kq = lane >> 4;
  const int brow = blockIdx.x * 256, bcol = blockIdx.y * 128;

  // swizzled per-lane read bases (row ≡ r mod 16 -> swz from r)
  const int swz = ((r >> 1) & 3) << 4;
  const int kb = (kq * 16) ^ swz;
  const int aRd = (wm * 64 + r) * 64 + kb;               // +buf*16384 + mf*1024
  const int bRd = 32768 + (wn * 64 + r) * 64 + kb;       // +buf*8192  + nf*1024

  // staging: dest linear tid*16; src pre-inverse-swizzled (rule #21)
  const int srow = tid >> 2;                              // 0..127
  const int sbyte = ((tid & 3) * 16) ^ (((srow >> 1) & 3) << 4);
  const char* aSrc = Ab + (size_t)(brow + srow) * 1024 + sbyte;   // rows srow, srow+128
  const char* bSrc = Bb + (size_t)(bcol + srow) * 1024 + sbyte;   // rows 0..127

#define STG_A(buf, kt) do { \
    const char* s_ = aSrc + (kt) * 64; \
    char* d_ = ldsb + (buf) * 16384 + tid * 16; \
    GLOAD16(s_, d_); GLOAD16(s_ + 131072, d_ + 8192); } while (0)
#define STG_B(buf, kt) GLOAD16(bSrc + (kt) * 64, ldsb + 32768 + (buf) * 8192 + tid * 16)
#define RDA(buf, mf) (*(const i32x4*)(ldsb + aRd + (buf) * 16384 + (mf) * 1024))
#define RDB(buf, nf) (*(const i32x4*)(ldsb + bRd + (buf) * 8192 + (nf) * 1024))
#define VMW3 asm volatile("s_waitcnt vmcnt(3)" ::: "memory")
#define VMW0 asm volatile("s_waitcnt vmcnt(0)" ::: "memory")
#define BAR __builtin_amdgcn_s_barrier()
#define MF(a, b, c) __builtin_amdgcn_mfma_i32_16x16x64_i8((a), (b), (c), 0, 0, 0)
#define LDB_ALL(buf) do { b0 = RDB(buf, 0); b1 = RDB(buf, 1); \
    b2 = RDB(buf, 2); b3 = RDB(buf, 3); } while (0)
#define MMQ(q, a_) do { \
    acc[q][0] = MF(a_, b0, acc[q][0]); acc[q][1] = MF(a_, b1, acc[q][1]); \
    acc[q][2] = MF(a_, b2, acc[q][2]); acc[q][3] = MF(a_, b3, acc[q][3]); } while (0)

  i32x4 acc[4][4] = {};
  i32x4 a0, a1, b0, b1, b2, b3;

  // prologue: tile0 + tile1 staged = 6 loads in flight
  STG_A(0, 0); STG_B(0, 0); STG_A(1, 1); STG_B(1, 1);

  for (int kt = 0; kt < 14; ++kt) {
    const int buf = kt & 1;
    VMW3; BAR;                                 // tile kt landed (kt+1's 3 in flight)
    LDB_ALL(buf); a0 = RDA(buf, 0); a1 = RDA(buf, 1);
    __builtin_amdgcn_s_setprio(1); MMQ(0, a0); MMQ(1, a1); __builtin_amdgcn_s_setprio(0);
    BAR;                                       // phase-0 reads retired by all waves
    a0 = RDA(buf, 2); a1 = RDA(buf, 3);
    __builtin_amdgcn_s_setprio(1); MMQ(2, a0); MMQ(3, a1); __builtin_amdgcn_s_setprio(0);
    BAR;                                       // ALL reads of buf retired -> restage
    STG_A(buf, kt + 2); STG_B(buf, kt + 2);
  }
  // kt=14 (buf 0): nothing more to stage
  VMW3; BAR;
  LDB_ALL(0); a0 = RDA(0, 0); a1 = RDA(0, 1);
  __builtin_amdgcn_s_setprio(1); MMQ(0, a0); MMQ(1, a1); __builtin_amdgcn_s_setprio(0);
  BAR;
  a0 = RDA(0, 2); a1 = RDA(0, 3);
  __builtin_amdgcn_s_setprio(1); MMQ(2, a0); MMQ(3, a1); __builtin_amdgcn_s_setprio(0);
  // kt=15 (buf 1)
  VMW0; BAR;
  LDB_ALL(1); a0 = RDA(1, 0); a1 = RDA(1, 1);
  __builtin_amdgcn_s_setprio(1); MMQ(0, a0); MMQ(1, a1); __builtin_amdgcn_s_setprio(0);
  BAR;
  a0 = RDA(1, 2); a1 = RDA(1, 3);
  __builtin_amdgcn_s_setprio(1); MMQ(2, a0); MMQ(3, a1); __builtin_amdgcn_s_setprio(0);
  BAR;                                         // LDS free for reuse

  // ---- epilogue: dequant+bias+ELU, quantize P into LDS pack, col sums ----
  const float DQ = (6.0f / 127.0f) * (0.03125f / 127.0f);
  const int cl = wn * 64 + r;                  // col within 128-wide tile (per nf: +16*nf... see below)
  float bv[4], cs[4] = {0.f, 0.f, 0.f, 0.f};
#pragma unroll
  for (int nf = 0; nf < 4; ++nf) bv[nf] = bias[bcol + wn * 64 + nf * 16 + r];
#pragma unroll
  for (int mf = 0; mf < 4; ++mf)
#pragma unroll
    for (int nf = 0; nf < 4; ++nf)
#pragma unroll
      for (int j = 0; j < 4; ++j) {
        float v = (float)acc[mf][nf][j] * DQ + bv[nf];
        v = v > 0.f ? v : (__expf(v) - 1.f);
        cs[nf] += v;
        int q = __float2int_rn(v * SP_INV);
        q = q > 127 ? 127 : (q < -127 ? -127 : q);
        int row = wm * 64 + mf * 16 + kq * 4 + j;    // C/D: col=lane&15, row=(lane>>4)*4+j
        ldsb[row * 128 + wn * 64 + nf * 16 + r] = (char)q;
      }
  // per-wave col partial over its 16 owned rows x kq: reduce across kq
#pragma unroll
  for (int nf = 0; nf < 4; ++nf) {
    cs[nf] += __shfl_xor(cs[nf], 16);
    cs[nf] += __shfl_xor(cs[nf], 32);
  }
  // wm==0 seeds scol; others LDS-atomic; one global atomic per col per block
  if (wm == 0 && kq == 0) {
#pragma unroll
    for (int nf = 0; nf < 4; ++nf) scol[wn * 64 + nf * 16 + r] = cs[nf];
  }
  __syncthreads();
  if (wm != 0 && kq == 0) {
#pragma unroll
    for (int nf = 0; nf < 4; ++nf) atomicAdd(&scol[wn * 64 + nf * 16 + r], cs[nf]);
  }
  // coalesced P stores (pack complete since the first __syncthreads above)
#pragma unroll
  for (int i = 0; i < 4; ++i) {
    int c = i * 512 + tid;                     // 2048 chunks of 16 B
    int row = c >> 3, coff = (c & 7) * 16;
    *(uint4*)(P + (size_t)(brow + row) * MDIM + bcol + coff) =
        *(const uint4*)(ldsb + row * 128 + coff);
  }
  __syncthreads();
  if (wm == 0 && kq == 0) {
#pragma unroll
    for (int nf = 0; nf < 4; ++nf)
      atomicAdd(&S[bcol + wn * 64 + nf * 16 + r], scol[wn * 64 + nf * 16 + r]);
  }
#undef STG_A
#undef STG_B
#undef RDA
#undef RDB
#undef VMW3
#undef VMW0
#undef BAR
#undef MF
#undef LDB_ALL
#undef MMQ
}

// ---- logits[row] = DQ_P * dot(Pq[row,:], s); one wave per row ----
__global__ __launch_bounds__(256) void gemv_logits_k(
    const char* __restrict__ P1, const char* __restrict__ P2,
    const float* __restrict__ S1, const float* __restrict__ S2,
    float* __restrict__ L) {
  int z = blockIdx.z;
  const char* P = z ? P2 : P1;
  const float* s = z ? S1 : S2;   // logits_a uses s2, logits_b uses s1
  float* Lz = L + (size_t)z * 8192;
  int wave = threadIdx.x >> 6, lane = threadIdx.x & 63;
  int row = blockIdx.x * 4 + wave;
  uint4 w = *(const uint4*)(P + (size_t)row * MDIM + lane * 16);
  const float4* sv = reinterpret_cast<const float4*>(s + lane * 16);
  float4 s0 = sv[0], s1v = sv[1], s2v = sv[2], s3v = sv[3];
  float acc =
      (float)(char)(w.x) * s0.x + (float)(char)(w.x >> 8) * s0.y +
      (float)(char)(w.x >> 16) * s0.z + (float)(char)(w.x >> 24) * s0.w +
      (float)(char)(w.y) * s1v.x + (float)(char)(w.y >> 8) * s1v.y +
      (float)(char)(w.y >> 16) * s1v.z + (float)(char)(w.y >> 24) * s1v.w +
      (float)(char)(w.z) * s2v.x + (float)(char)(w.z >> 8) * s2v.y +
      (float)(char)(w.z >> 16) * s2v.z + (float)(char)(w.z >> 24) * s2v.w +
      (float)(char)(w.w) * s3v.x + (float)(char)(w.w >> 8) * s3v.y +
      (float)(char)(w.w >> 16) * s3v.z + (float)(char)(w.w >> 24) * s3v.w;
  for (int o = 32; o; o >>= 1) acc += __shfl_down(acc, o);
  if (lane == 0) Lz[row] = acc * DQ_P;
}

// ---- att: block-local softmax over logits + weighted row-sum of i8 seq ----
// 64 blocks/problem x 128 rows each; err <= 6/254 = 0.024 (convex combo).
__global__ __launch_bounds__(256) void att_sm_k(const char* __restrict__ s1b,
    const char* __restrict__ s2b, const float* __restrict__ logits,
    float* __restrict__ out) {
  int z = blockIdx.z;
  const char* seq = z ? s2b : s1b;
  const float* L = logits + (size_t)z * 8192;
  float* o = out + (size_t)z * EDIM;
  __shared__ float red[256];
  __shared__ float wsm[128];
  int tid = threadIdx.x;

  float lv[32];
  float m = -3.4e38f;
#pragma unroll
  for (int k = 0; k < 32; ++k) { lv[k] = L[tid + k * 256]; m = fmaxf(m, lv[k]); }
  red[tid] = m; __syncthreads();
  for (int s = 128; s; s >>= 1) {
    if (tid < s) red[tid] = fmaxf(red[tid], red[tid + s]);
    __syncthreads();
  }
  m = red[0]; __syncthreads();
  float sum = 0.f;
#pragma unroll
  for (int k = 0; k < 32; ++k) sum += __expf(lv[k] - m);
  red[tid] = sum; __syncthreads();
  for (int s = 128; s; s >>= 1) {
    if (tid < s) red[tid] += red[tid + s];
    __syncthreads();
  }
  float inv = 1.f / red[0];

  int a0 = blockIdx.y * 128;
  if (tid < 128) wsm[tid] = __expf(L[a0 + tid] - m) * inv;
  __syncthreads();

  float c0 = 0.f, c1 = 0.f, c2 = 0.f, c3 = 0.f;
  const char* p = seq + (size_t)a0 * EDIM + tid * 4;
#pragma unroll 4
  for (int j = 0; j < 128; ++j, p += EDIM) {
    float wa = wsm[j];
    unsigned v = *reinterpret_cast<const unsigned*>(p);
    c0 += wa * (float)(char)(v);
    c1 += wa * (float)(char)(v >> 8);
    c2 += wa * (float)(char)(v >> 16);
    c3 += wa * (float)(char)(v >> 24);
  }
  atomicAdd(&o[tid * 4 + 0], c0 * DQ_A);
  atomicAdd(&o[tid * 4 + 1], c1 * DQ_A);
  atomicAdd(&o[tid * 4 + 2], c2 * DQ_A);
  atomicAdd(&o[tid * 4 + 3], c3 * DQ_A);
}

extern "C" void kernel_launch(void* const* d_in, const int* in_sizes, int n_in,
                              void* d_out, int out_size, void* d_ws, size_t ws_size,
                              hipStream_t stream) {
  const float* seq1 = (const float*)d_in[0];
  const float* seq2 = (const float*)d_in[1];
  const float* ctx  = (const float*)d_in[2];
  const float* Wc1  = (const float*)d_in[3];
  const float* Wc2  = (const float*)d_in[4];
  const float* W1   = (const float*)d_in[5];
  const float* b1   = (const float*)d_in[6];
  const float* W2   = (const float*)d_in[7];
  const float* b2   = (const float*)d_in[8];
  float* out = (float*)d_out;
  char* ws = (char*)d_ws;

  float* bias1 = (float*)(ws + OFF_BIAS1);
  float* bias2 = (float*)(ws + OFF_BIAS2);
  float* s1    = (float*)(ws + OFF_S1);
  float* s2    = (float*)(ws + OFF_S2);
  float* loga  = (float*)(ws + OFF_LOGA);
  char* p1     = (char*)(ws + OFF_P1);
  char* p2     = (char*)(ws + OFF_P2);
  char* seq1b  = (char*)(ws + OFF_SEQ1B);     // i8
  char* seq2b  = (char*)(ws + OFF_SEQ2B);
  char* w1b    = (char*)(ws + OFF_W1B);       // i8
  char* w2b    = (char*)(ws + OFF_W2B);

  prep_k<<<dim3(512, 1, 5), 256, 0, stream>>>(
      seq1, seq2, W1, W2, (uint2*)seq1b, (uint2*)seq2b, (uint2*)w1b, (uint2*)w2b,
      Wc1, Wc2, ctx, b1, b2, bias1, bias2, s1, s2, out);

  gemm8<<<dim3(A_ROWS / 256, MDIM / 128, 2), 512, 0, stream>>>(
      seq1b, seq2b, w1b, w2b, bias1, bias2, p1, p2, s1, s2);

  gemv_logits_k<<<dim3(2048, 1, 2), 256, 0, stream>>>(p1, p2, s1, s2, loga);

  att_sm_k<<<dim3(1, 64, 2), 256, 0, stream>>>(seq1b, seq2b, loga, out);
}

// Round 13
// 67.693 us; speedup vs baseline: 1.0250x; 1.0250x over previous
//
#include <hip/hip_runtime.h>
#include <hip/hip_bf16.h>

// OuterAttention: A=B=8192, E1=E2=C=M=1024.
// logits_a = p1 @ sum(p2), logits_b = p2 @ sum(p1) -> no 8192^2 matrix.
// Round 13: i8 BK=128 GEMM with R6's EXACT fine 8-phase interleave (the
// coarse LDB_ALL 4-phase of R10/R11 is the m196 regression mode). Byte-
// identical LDS geometry to R6 (128-B rows), 8 K-tiles, peeled tail.

#define A_ROWS 8192
#define EDIM   1024
#define MDIM   1024

typedef __attribute__((ext_vector_type(8))) short bf16x8;
typedef __attribute__((ext_vector_type(4))) int i32x4;

// ---- workspace layout (bytes) ----
#define OFF_BIAS1   0ull
#define OFF_BIAS2   4096ull
#define OFF_S1      8192ull
#define OFF_S2      12288ull
#define OFF_LOGA    16384ull                  // 2 x 8192 floats (raw logits)
#define OFF_P1      81920ull                  // 8192*1024 i8 = 8 MB
#define OFF_P2      (OFF_P1 + 16777216ull)
#define OFF_SEQ1B   (OFF_P2 + 16777216ull)    // i8: 8 MB
#define OFF_SEQ2B   (OFF_SEQ1B + 16777216ull)
#define OFF_W1B     (OFF_SEQ2B + 16777216ull) // i8: 1 MB
#define OFF_W2B     (OFF_W1B + 2097152ull)

#define SA_INV 21.166666f        // 127/6   (seq quant)
#define SW_INV 4064.0f           // 127/(1/32)  (W quant)
#define SP_INV 25.4f             // 127/5   (P quant)
#define DQ_P   (5.0f / 127.0f)
#define DQ_A   (6.0f / 127.0f)

__device__ __forceinline__ unsigned pack4(float4 f, float s) {
  int q0 = __float2int_rn(f.x * s); q0 = q0 > 127 ? 127 : (q0 < -127 ? -127 : q0);
  int q1 = __float2int_rn(f.y * s); q1 = q1 > 127 ? 127 : (q1 < -127 ? -127 : q1);
  int q2 = __float2int_rn(f.z * s); q2 = q2 > 127 ? 127 : (q2 < -127 ? -127 : q2);
  int q3 = __float2int_rn(f.w * s); q3 = q3 > 127 ? 127 : (q3 < -127 ? -127 : q3);
  return (q0 & 255) | ((q1 & 255) << 8) | ((q2 & 255) << 16) | ((q3 & 255) << 24);
}

#define GLOAD16(src, dst) __builtin_amdgcn_global_load_lds( \
    (const __attribute__((address_space(1))) void*)(src),   \
    (__attribute__((address_space(3))) void*)(dst), 16, 0, 0)

// ---- prep: f32 -> i8 quantize (z=0..3) + ctx bias / S zero / out zero (z=4) ----
__global__ __launch_bounds__(256) void prep_k(
    const float* __restrict__ s1, const float* __restrict__ s2,
    const float* __restrict__ w1, const float* __restrict__ w2,
    uint2* __restrict__ s1o, uint2* __restrict__ s2o,
    uint2* __restrict__ w1o, uint2* __restrict__ w2o,
    const float* __restrict__ Wc1, const float* __restrict__ Wc2,
    const float* __restrict__ ctx, const float* __restrict__ b1,
    const float* __restrict__ b2, float* __restrict__ bias1,
    float* __restrict__ bias2, float* __restrict__ S1, float* __restrict__ S2,
    float* __restrict__ outz) {
  int z = blockIdx.z;
  if (z < 4) {
    const float* in = z == 0 ? s1 : z == 1 ? s2 : z == 2 ? w1 : w2;
    uint2* out = z == 0 ? s1o : z == 1 ? s2o : z == 2 ? w1o : w2o;
    float sc = z < 2 ? SA_INV : SW_INV;
    int n8 = z < 2 ? (A_ROWS * EDIM / 8) : (MDIM * EDIM / 8);
    int stride = gridDim.x * blockDim.x;
    for (int i = blockIdx.x * blockDim.x + threadIdx.x; i < n8; i += stride) {
      float4 fa = reinterpret_cast<const float4*>(in)[2 * i];
      float4 fb = reinterpret_cast<const float4*>(in)[2 * i + 1];
      out[i] = make_uint2(pack4(fa, sc), pack4(fb, sc));
    }
  } else {
    if (blockIdx.x == 0) {                       // zero the 2048-float output
      float4 zv = make_float4(0.f, 0.f, 0.f, 0.f);
      ((float4*)outz)[threadIdx.x] = zv;
      ((float4*)outz)[threadIdx.x + 256] = zv;
    }
    if (blockIdx.x >= 512) return;
    int zz = blockIdx.x >= 256;                  // 0: problem1, 1: problem2
    int bx = blockIdx.x & 255;
    const float* W = zz ? Wc2 : Wc1;
    const float* b = zz ? b2 : b1;
    float* bias = zz ? bias2 : bias1;
    float* S = zz ? S2 : S1;
    int wave = threadIdx.x >> 6, lane = threadIdx.x & 63;
    int m = bx * 4 + wave;
    const float4* wr = reinterpret_cast<const float4*>(W + (size_t)m * EDIM);
    const float4* cv = reinterpret_cast<const float4*>(ctx);
    float acc = 0.f;
#pragma unroll
    for (int ch = 0; ch < 4; ++ch) {
      float4 a = wr[ch * 64 + lane], d = cv[ch * 64 + lane];
      acc += a.x * d.x + a.y * d.y + a.z * d.z + a.w * d.w;
    }
    for (int o = 32; o; o >>= 1) acc += __shfl_down(acc, o);
    if (lane == 0) { bias[m] = acc + b[m]; S[m] = 0.f; }
  }
}

// ---- 256x256 i8 GEMM, BK=128, 8 K-tiles, R6 8-phase schedule ----
// 8 waves (2M x 4N). LDS bytes: A buf b @ b*32768 (half h @ +h*16384);
// B @ 65536 + b*32768 (+h*16384). Rows are 128 B (128 i8). Swizzle
// byte ^= (row&7)<<4 both-sides. VMW4 per half-iteration; peeled tail.
__global__ __launch_bounds__(512) void gemm8(
    const char* __restrict__ A1, const char* __restrict__ A2,
    const char* __restrict__ B1, const char* __restrict__ B2,
    const float* __restrict__ bias1, const float* __restrict__ bias2,
    char* __restrict__ P1, char* __restrict__ P2,
    float* __restrict__ S1, float* __restrict__ S2) {
  const int z = blockIdx.z;
  const char* __restrict__ Ab = z ? A2 : A1;
  const char* __restrict__ Bb = z ? B2 : B1;
  const float* __restrict__ bias = z ? bias2 : bias1;
  char* __restrict__ P = z ? P2 : P1;
  float* __restrict__ S = z ? S2 : S1;

  __shared__ __align__(16) char ldsb[131072];   // 128 KB

  const int tid = threadIdx.x;
  const int lane = tid & 63;
  const int wave = tid >> 6;
  const int wm = wave >> 2, wn = wave & 3;
  const int r = lane & 15, kq = lane >> 4;
  const int brow = blockIdx.x * 256, bcol = blockIdx.y * 256;
  const int wrow = wm * 128, wcol = wn * 64;

  // swizzled per-lane LDS read bases (k-slot 0 / 1 of the 128-i8 K window)
  const int xm = (r & 7) << 4;
  const int aB0 = wm * 16384 + r * 128 + ((kq * 16) ^ xm);
  const int aB1 = wm * 16384 + r * 128 + ((64 + kq * 16) ^ xm);
  const int bRow = (wn & 1) * 64 + r;
  const int bB0 = 65536 + (wn >> 1) * 16384 + bRow * 128 + ((kq * 16) ^ xm);
  const int bB1 = 65536 + (wn >> 1) * 16384 + bRow * 128 + ((64 + kq * 16) ^ xm);

  // staging source: pre-inverse-swizzled global address (rule #21)
  const int srow = tid >> 3;                               // 0..63
  const int scb = ((tid & 7) * 16) ^ ((srow & 7) << 4);
  const char* aSrc = Ab + (size_t)(brow + srow) * 1024 + scb;
  const char* bSrc = Bb + (size_t)(bcol + srow) * 1024 + scb;

// half h = rows h*128..h*128+127; 2 loads/thread (rows srow, srow+64)
#define STG_A(buf, h, kt) do { \
    const char* s_ = aSrc + (h) * 131072 + (kt) * 128; \
    char* d_ = ldsb + (buf) * 32768 + (h) * 16384 + tid * 16; \
    GLOAD16(s_, d_); GLOAD16(s_ + 65536, d_ + 8192); } while (0)
#define STG_B(buf, h, kt) do { \
    const char* s_ = bSrc + (h) * 131072 + (kt) * 128; \
    char* d_ = ldsb + 65536 + (buf) * 32768 + (h) * 16384 + tid * 16; \
    GLOAD16(s_, d_); GLOAD16(s_ + 65536, d_ + 8192); } while (0)
#define RD_A0(buf, mf) (*(const i32x4*)(ldsb + aB0 + (buf) * 32768 + (mf) * 2048))
#define RD_A1(buf, mf) (*(const i32x4*)(ldsb + aB1 + (buf) * 32768 + (mf) * 2048))
#define RD_B0(buf, nf) (*(const i32x4*)(ldsb + bB0 + (buf) * 32768 + (nf) * 2048))
#define RD_B1(buf, nf) (*(const i32x4*)(ldsb + bB1 + (buf) * 32768 + (nf) * 2048))
#define VMW4 asm volatile("s_waitcnt vmcnt(4)" ::: "memory")
#define VMW0 asm volatile("s_waitcnt vmcnt(0)" ::: "memory")
#define BAR __builtin_amdgcn_s_barrier()
#define MF(a, b, c) __builtin_amdgcn_mfma_i32_16x16x64_i8((a), (b), (c), 0, 0, 0)
#define LDA(buf, mf0) do { a0k0 = RD_A0(buf, mf0); a0k1 = RD_A1(buf, mf0); \
    a1k0 = RD_A0(buf, (mf0) + 1); a1k1 = RD_A1(buf, (mf0) + 1); } while (0)
#define LDB(buf) do { \
    b0k0 = RD_B0(buf, 0); b0k1 = RD_B1(buf, 0); b1k0 = RD_B0(buf, 1); b1k1 = RD_B1(buf, 1); \
    b2k0 = RD_B0(buf, 2); b2k1 = RD_B1(buf, 2); b3k0 = RD_B0(buf, 3); b3k1 = RD_B1(buf, 3); } while (0)
#define QUAD(q) do { __builtin_amdgcn_s_setprio(1); \
    acc[q][0] = MF(a0k0, b0k0, acc[q][0]); acc[q][0] = MF(a0k1, b0k1, acc[q][0]); \
    acc[q][1] = MF(a0k0, b1k0, acc[q][1]); acc[q][1] = MF(a0k1, b1k1, acc[q][1]); \
    acc[q][2] = MF(a0k0, b2k0, acc[q][2]); acc[q][2] = MF(a0k1, b2k1, acc[q][2]); \
    acc[q][3] = MF(a0k0, b3k0, acc[q][3]); acc[q][3] = MF(a0k1, b3k1, acc[q][3]); \
    acc[(q)+1][0] = MF(a1k0, b0k0, acc[(q)+1][0]); acc[(q)+1][0] = MF(a1k1, b0k1, acc[(q)+1][0]); \
    acc[(q)+1][1] = MF(a1k0, b1k0, acc[(q)+1][1]); acc[(q)+1][1] = MF(a1k1, b1k1, acc[(q)+1][1]); \
    acc[(q)+1][2] = MF(a1k0, b2k0, acc[(q)+1][2]); acc[(q)+1][2] = MF(a1k1, b2k1, acc[(q)+1][2]); \
    acc[(q)+1][3] = MF(a1k0, b3k0, acc[(q)+1][3]); acc[(q)+1][3] = MF(a1k1, b3k1, acc[(q)+1][3]); \
    __builtin_amdgcn_s_setprio(0); } while (0)

  i32x4 acc[8][4] = {};
  i32x4 a0k0, a0k1, a1k0, a1k1;
  i32x4 b0k0, b0k1, b1k0, b1k1, b2k0, b2k1, b3k0, b3k1;

  // prologue: buf0 <- tile 0 (B halves then A halves), buf1.B <- tile 1
  STG_B(0, 0, 0); STG_B(0, 1, 0); STG_A(0, 0, 0); STG_A(0, 1, 0);
  STG_B(1, 0, 1); STG_B(1, 1, 1);                 // 12 loads in flight

  for (int it = 0; it < 3; ++it) {                // tiles 0..5
    const int k1 = 2 * it + 1;
    const int k2 = 2 * it + 2;
    const int k3 = 2 * it + 3;
    // ---- K-tile 2it (buf0), phases 0-3 ----
    VMW4; BAR;                                 // buf0 tile fully landed (all waves)
    LDB(0); LDA(0, 0); STG_A(1, 0, k1); QUAD(0);
    BAR; LDA(0, 2); STG_A(1, 1, k1); QUAD(2);
    BAR; LDA(0, 4); STG_B(0, 0, k2); QUAD(4);
    BAR; LDA(0, 6); STG_B(0, 1, k2); QUAD(6);
    // ---- K-tile 2it+1 (buf1), phases 4-7 ----
    VMW4; BAR;                                 // buf1 tile landed
    LDB(1); LDA(1, 0); STG_A(0, 0, k2); QUAD(0);
    BAR; LDA(1, 2); STG_A(0, 1, k2); QUAD(2);
    BAR; LDA(1, 4); STG_B(1, 0, k3); QUAD(4);
    BAR; LDA(1, 6); STG_B(1, 1, k3); QUAD(6);
  }
  // ---- peeled: tile 6 (buf0); tile 7 (buf1, B staged at it=2) ----
  VMW4; BAR;
  LDB(0); LDA(0, 0); STG_A(1, 0, 7); QUAD(0);
  BAR; LDA(0, 2); STG_A(1, 1, 7); QUAD(2);
  BAR; LDA(0, 4); QUAD(4);
  BAR; LDA(0, 6); QUAD(6);
  VMW0; BAR;                                   // tile 7 fully landed; queue empty
  LDB(1); LDA(1, 0); QUAD(0);
  BAR; LDA(1, 2); QUAD(2);
  BAR; LDA(1, 4); QUAD(4);
  BAR; LDA(1, 6); QUAD(6);
  BAR;                                         // all LDS reads consumed -> reuse

  // ---- epilogue: dequant + bias + ELU, col sums, quantize P to i8, pack ----
  const float DQ = (6.0f / 127.0f) * (0.03125f / 127.0f);
  char* pl = ldsb;                              // 256x256 i8 = 64 KB
  float bv[4], cs[4] = {0.f, 0.f, 0.f, 0.f};
#pragma unroll
  for (int nf = 0; nf < 4; ++nf) bv[nf] = bias[bcol + wcol + nf * 16 + r];
#pragma unroll
  for (int mf = 0; mf < 8; ++mf)
#pragma unroll
    for (int nf = 0; nf < 4; ++nf)
#pragma unroll
      for (int j = 0; j < 4; ++j) {
        float v = (float)acc[mf][nf][j] * DQ + bv[nf];
        v = v > 0.f ? v : (__expf(v) - 1.f);
        cs[nf] += v;
        int q = __float2int_rn(v * SP_INV);
        q = q > 127 ? 127 : (q < -127 ? -127 : q);
        int row = wrow + mf * 16 + kq * 4 + j;       // C/D: col=lane&15, row=(lane>>4)*4+j
        pl[row * 256 + wcol + nf * 16 + r] = (char)q;
      }
#pragma unroll
  for (int nf = 0; nf < 4; ++nf) {
    cs[nf] += __shfl_xor(cs[nf], 16);
    cs[nf] += __shfl_xor(cs[nf], 32);
    if (kq == 0) atomicAdd(&S[bcol + wcol + nf * 16 + r], cs[nf]);
  }
  __syncthreads();
#pragma unroll
  for (int i = 0; i < 8; ++i) {
    int c = i * 512 + tid;                           // 4096 chunks of 16 B
    int row = c >> 4, coff = (c & 15) * 16;
    *(uint4*)(P + (size_t)(brow + row) * MDIM + bcol + coff) =
        *(const uint4*)(pl + row * 256 + coff);
  }
#undef STG_A
#undef STG_B
#undef RD_A0
#undef RD_A1
#undef RD_B0
#undef RD_B1
#undef VMW4
#undef VMW0
#undef BAR
#undef MF
#undef LDA
#undef LDB
#undef QUAD
}

// ---- logits[row] = DQ_P * dot(Pq[row,:], s); one wave per row ----
__global__ __launch_bounds__(256) void gemv_logits_k(
    const char* __restrict__ P1, const char* __restrict__ P2,
    const float* __restrict__ S1, const float* __restrict__ S2,
    float* __restrict__ L) {
  int z = blockIdx.z;
  const char* P = z ? P2 : P1;
  const float* s = z ? S1 : S2;   // logits_a uses s2, logits_b uses s1
  float* Lz = L + (size_t)z * 8192;
  int wave = threadIdx.x >> 6, lane = threadIdx.x & 63;
  int row = blockIdx.x * 4 + wave;
  uint4 w = *(const uint4*)(P + (size_t)row * MDIM + lane * 16);
  const float4* sv = reinterpret_cast<const float4*>(s + lane * 16);
  float4 s0 = sv[0], s1v = sv[1], s2v = sv[2], s3v = sv[3];
  float acc =
      (float)(char)(w.x) * s0.x + (float)(char)(w.x >> 8) * s0.y +
      (float)(char)(w.x >> 16) * s0.z + (float)(char)(w.x >> 24) * s0.w +
      (float)(char)(w.y) * s1v.x + (float)(char)(w.y >> 8) * s1v.y +
      (float)(char)(w.y >> 16) * s1v.z + (float)(char)(w.y >> 24) * s1v.w +
      (float)(char)(w.z) * s2v.x + (float)(char)(w.z >> 8) * s2v.y +
      (float)(char)(w.z >> 16) * s2v.z + (float)(char)(w.z >> 24) * s2v.w +
      (float)(char)(w.w) * s3v.x + (float)(char)(w.w >> 8) * s3v.y +
      (float)(char)(w.w >> 16) * s3v.z + (float)(char)(w.w >> 24) * s3v.w;
  for (int o = 32; o; o >>= 1) acc += __shfl_down(acc, o);
  if (lane == 0) Lz[row] = acc * DQ_P;
}

// ---- att: block-local softmax over logits + weighted row-sum of i8 seq ----
// 64 blocks/problem x 128 rows each; err <= 6/254 = 0.024 (convex combo).
__global__ __launch_bounds__(256) void att_sm_k(const char* __restrict__ s1b,
    const char* __restrict__ s2b, const float* __restrict__ logits,
    float* __restrict__ out) {
  int z = blockIdx.z;
  const char* seq = z ? s2b : s1b;
  const float* L = logits + (size_t)z * 8192;
  float* o = out + (size_t)z * EDIM;
  __shared__ float red[256];
  __shared__ float wsm[128];
  int tid = threadIdx.x;

  float lv[32];
  float m = -3.4e38f;
#pragma unroll
  for (int k = 0; k < 32; ++k) { lv[k] = L[tid + k * 256]; m = fmaxf(m, lv[k]); }
  red[tid] = m; __syncthreads();
  for (int s = 128; s; s >>= 1) {
    if (tid < s) red[tid] = fmaxf(red[tid], red[tid + s]);
    __syncthreads();
  }
  m = red[0]; __syncthreads();
  float sum = 0.f;
#pragma unroll
  for (int k = 0; k < 32; ++k) sum += __expf(lv[k] - m);
  red[tid] = sum; __syncthreads();
  for (int s = 128; s; s >>= 1) {
    if (tid < s) red[tid] += red[tid + s];
    __syncthreads();
  }
  float inv = 1.f / red[0];

  int a0 = blockIdx.y * 128;
  if (tid < 128) wsm[tid] = __expf(L[a0 + tid] - m) * inv;
  __syncthreads();

  float c0 = 0.f, c1 = 0.f, c2 = 0.f, c3 = 0.f;
  const char* p = seq + (size_t)a0 * EDIM + tid * 4;
#pragma unroll 4
  for (int j = 0; j < 128; ++j, p += EDIM) {
    float wa = wsm[j];
    unsigned v = *reinterpret_cast<const unsigned*>(p);
    c0 += wa * (float)(char)(v);
    c1 += wa * (float)(char)(v >> 8);
    c2 += wa * (float)(char)(v >> 16);
    c3 += wa * (float)(char)(v >> 24);
  }
  atomicAdd(&o[tid * 4 + 0], c0 * DQ_A);
  atomicAdd(&o[tid * 4 + 1], c1 * DQ_A);
  atomicAdd(&o[tid * 4 + 2], c2 * DQ_A);
  atomicAdd(&o[tid * 4 + 3], c3 * DQ_A);
}

extern "C" void kernel_launch(void* const* d_in, const int* in_sizes, int n_in,
                              void* d_out, int out_size, void* d_ws, size_t ws_size,
                              hipStream_t stream) {
  const float* seq1 = (const float*)d_in[0];
  const float* seq2 = (const float*)d_in[1];
  const float* ctx  = (const float*)d_in[2];
  const float* Wc1  = (const float*)d_in[3];
  const float* Wc2  = (const float*)d_in[4];
  const float* W1   = (const float*)d_in[5];
  const float* b1   = (const float*)d_in[6];
  const float* W2   = (const float*)d_in[7];
  const float* b2   = (const float*)d_in[8];
  float* out = (float*)d_out;
  char* ws = (char*)d_ws;

  float* bias1 = (float*)(ws + OFF_BIAS1);
  float* bias2 = (float*)(ws + OFF_BIAS2);
  float* s1    = (float*)(ws + OFF_S1);
  float* s2    = (float*)(ws + OFF_S2);
  float* loga  = (float*)(ws + OFF_LOGA);
  char* p1     = (char*)(ws + OFF_P1);
  char* p2     = (char*)(ws + OFF_P2);
  char* seq1b  = (char*)(ws + OFF_SEQ1B);     // i8
  char* seq2b  = (char*)(ws + OFF_SEQ2B);
  char* w1b    = (char*)(ws + OFF_W1B);       // i8
  char* w2b    = (char*)(ws + OFF_W2B);

  prep_k<<<dim3(512, 1, 5), 256, 0, stream>>>(
      seq1, seq2, W1, W2, (uint2*)seq1b, (uint2*)seq2b, (uint2*)w1b, (uint2*)w2b,
      Wc1, Wc2, ctx, b1, b2, bias1, bias2, s1, s2, out);

  gemm8<<<dim3(A_ROWS / 256, MDIM / 256, 2), 512, 0, stream>>>(
      seq1b, seq2b, w1b, w2b, bias1, bias2, p1, p2, s1, s2);

  gemv_logits_k<<<dim3(2048, 1, 2), 256, 0, stream>>>(p1, p2, s1, s2, loga);

  att_sm_k<<<dim3(1, 64, 2), 256, 0, stream>>>(seq1b, seq2b, loga, out);
}